// Round 9
// baseline (155.339 us; speedup 1.0000x reference)
//
#include <hip/hip_runtime.h>
#include <math.h>

// GAT aggregation: B=8,S=512,N=32,H=256,V=100001
// One BLOCK (8 waves, 512 thr) per position. Masked neighbors have softmax
// weight exactly +0 (exp(-1e9-m) underflows) and are never loaded; ~17 of 33
// candidates survive. Round-9 changes vs round 8 (152.1 us):
//  - 8 waves/position (was 4): ~2 candidates per wave -> shorter serial
//    online-softmax chain, 2x wave-level parallelism (32768 waves).
//  - redundant per-wave compaction: every wave loads the same index/mask
//    bytes (L1 broadcast), ballots, compacts into its own LDS slice
//    (same-wave DS ordering, no barrier) -> first __syncthreads removed;
//    waves no longer idle behind wave 0's index-load HBM round trip.
//  - only remaining barrier is the block merge of 8 partials.

constexpr int H    = 256;
constexpr int NN   = 32;                  // neighbors
constexpr int C    = NN + 1;              // max candidates (self + neighbors)
constexpr int WPB  = 8;                   // waves per block (= per position)
constexpr int JMAX = (C + WPB - 1) / WPB; // max candidates per wave = 5
constexpr float SLOPE = 0.2f;

__device__ __forceinline__ float wave_sum(float v) {
#pragma unroll
  for (int off = 32; off > 0; off >>= 1)
    v += __shfl_xor(v, off, 64);
  return v;
}

__global__ __launch_bounds__(512, 6) void gat_kernel(
    const int*   __restrict__ node_ids,   // [npos]
    const int*   __restrict__ neighs,     // [npos, NN]
    const int*   __restrict__ mask,       // [npos, NN]
    const float* __restrict__ emb,        // [V, H]
    const float* __restrict__ a_w,        // [2H]
    const float* __restrict__ a_b,        // [1]
    float*       __restrict__ out)        // [npos, H]
{
  __shared__ int    sidx[WPB][64];        // per-wave compacted survivor ids
  __shared__ float  smx[WPB], ssum[WPB];  // per-wave partial m, s
  __shared__ float4 sacc[WPB][64];        // per-wave partial acc (1 KB each)

  const int pos  = blockIdx.x;
  const int wv   = threadIdx.x >> 6;
  const int lane = threadIdx.x & 63;
  const int l4   = lane << 2;

  // ---- every wave: load indices/mask, ballot-compact into own LDS slice ----
  bool active = false;
  int  my     = 0;
  if (lane == 0) {
    my = node_ids[pos];
    active = true;                               // self never masked
  } else if (lane <= NN) {
    my     = neighs[pos * NN + lane - 1];
    active = (mask[pos * NN + lane - 1] == 0);   // masked -> weight +0 -> skip
  }
  const unsigned long long bal = __ballot(active);
  const int K = (int)__popcll(bal);              // wave-uniform (SGPR)
  if (active)
    sidx[wv][(int)__popcll(bal & ((1ull << lane) - 1ull))] = my;
  // Same-wave LDS write->read: DS ops execute in order within a wave.
  const int cidx = sidx[wv][lane];               // lane k = survivor k's id
  const int swv  = __builtin_amdgcn_readfirstlane(wv);

  const float4 aw1 = *(const float4*)(a_w + l4);        // src half of a_w
  const float4 aw2 = *(const float4*)(a_w + H + l4);    // candidate half
  const float  ab  = a_b[0];
  const float4* __restrict__ embv = (const float4*)emb; // row = H/4 float4

  // Self row (survivor 0) -> zsrc, needed by every wave (L1 broadcast).
  const int    iself = __builtin_amdgcn_readlane(cidx, 0);
  const float4 es    = embv[(size_t)iself * (H / 4) + lane];

  // Load this wave's candidate rows upfront (independent, all in flight).
  float4 buf[JMAX];
#pragma unroll
  for (int j = 0; j < JMAX; ++j) {
    const int c = swv + WPB * j;
    if (c < K) {                                          // scalar guard
      const int ic = __builtin_amdgcn_readlane(cidx, c);  // SGPR row index
      buf[j] = embv[(size_t)ic * (H / 4) + lane];
    }
  }

  const float zsrc = wave_sum(es.x * aw1.x + es.y * aw1.y +
                              es.z * aw1.z + es.w * aw1.w);

  // Partial online softmax over this wave's candidates.
  float  m = -1e30f, s = 0.f;
  float4 acc = {0.f, 0.f, 0.f, 0.f};
#pragma unroll
  for (int j = 0; j < JMAX; ++j) {
    const int c = swv + WPB * j;
    if (c < K) {
      const float4 cur = buf[j];
      const float  p   = wave_sum(cur.x * aw2.x + cur.y * aw2.y +
                                  cur.z * aw2.z + cur.w * aw2.w);
      const float z = zsrc + p + ab;
      const float a = (z > 0.f) ? z : SLOPE * z;          // LeakyReLU(0.2)
      const float mnew  = fmaxf(m, a);
      const float scale = __expf(m - mnew);
      const float pr    = __expf(a - mnew);
      s = s * scale + pr;
      acc.x = acc.x * scale + pr * cur.x;
      acc.y = acc.y * scale + pr * cur.y;
      acc.z = acc.z * scale + pr * cur.z;
      acc.w = acc.w * scale + pr * cur.w;
      m = mnew;
    }
  }

  // ---- block merge of the 8 partials (single barrier) ----
  sacc[wv][lane] = acc;
  if (lane == 0) { smx[wv] = m; ssum[wv] = s; }
  __syncthreads();

  if (wv == 0) {
    float M = -1e30f;
#pragma unroll
    for (int w = 0; w < WPB; ++w) M = fmaxf(M, smx[w]);
    float  S = 0.f;
    float4 o = {0.f, 0.f, 0.f, 0.f};
#pragma unroll
    for (int w = 0; w < WPB; ++w) {
      const float f = __expf(smx[w] - M);  // empty wave: exp(-1e30-M) = +0
      S += ssum[w] * f;
      const float4 a = sacc[w][lane];
      o.x += f * a.x; o.y += f * a.y; o.z += f * a.z; o.w += f * a.w;
    }
    const float inv = 1.f / S;
    o.x *= inv; o.y *= inv; o.z *= inv; o.w *= inv;
    *(float4*)(out + (size_t)pos * H + l4) = o;
  }
}

extern "C" void kernel_launch(void* const* d_in, const int* in_sizes, int n_in,
                              void* d_out, int out_size, void* d_ws, size_t ws_size,
                              hipStream_t stream) {
  const int*   node_ids = (const int*)d_in[0];
  const int*   neighs   = (const int*)d_in[1];
  const int*   mask     = (const int*)d_in[2];
  const float* emb      = (const float*)d_in[3];
  const float* a_w      = (const float*)d_in[4];
  const float* a_b      = (const float*)d_in[5];
  float*       out      = (float*)d_out;

  const int npos = in_sizes[0];           // B*S = 4096
  gat_kernel<<<npos, 512, 0, stream>>>(node_ids, neighs, mask, emb, a_w, a_b,
                                       out);
}

// Round 10
// 152.037 us; speedup vs baseline: 1.0217x; 1.0217x over previous
//
#include <hip/hip_runtime.h>
#include <math.h>

// GAT aggregation: B=8,S=512,N=32,H=256,V=100001
// One BLOCK (4 waves) per position; wave w owns survivors {w, w+4, ...}.
// Masked neighbors have softmax weight exactly +0 (exp(-1e9-m) underflows)
// and are never loaded; ~17 of 33 candidates survive.
// Round-10 = R8 (WPB=4, best measured) + two structural fixes:
//  - per-wave redundant compaction (no first __syncthreads): each wave loads
//    the same 260 B of indices/mask (L1 broadcast), ballots, compacts into
//    its own LDS slice; row loads issue immediately.
//  - two-pass softmax in-wave: one BATCHED butterfly reduces zsrc + all
//    candidate dots together (independent values -> pipelined DS ops),
//    replacing the serial online-softmax rescale chain.
// MLP model (R9 lesson): outstanding row-loads/CU = blocks/CU x K; keep
// 256-thr blocks at 5 waves/EU -> 5 blocks/CU resident.

constexpr int H    = 256;
constexpr int NN   = 32;                  // neighbors
constexpr int C    = NN + 1;              // max candidates (self + neighbors)
constexpr int WPB  = 4;                   // waves per block (= per position)
constexpr int JMAX = (C + WPB - 1) / WPB; // max candidates per wave = 9
constexpr int NR   = JMAX + 1;            // batched reduction width (zsrc + 9)
constexpr float SLOPE = 0.2f;

__global__ __launch_bounds__(256, 5) void gat_kernel(
    const int*   __restrict__ node_ids,   // [npos]
    const int*   __restrict__ neighs,     // [npos, NN]
    const int*   __restrict__ mask,       // [npos, NN]
    const float* __restrict__ emb,        // [V, H]
    const float* __restrict__ a_w,        // [2H]
    const float* __restrict__ a_b,        // [1]
    float*       __restrict__ out)        // [npos, H]
{
  __shared__ int    sidx[WPB][64];        // per-wave compacted survivor ids
  __shared__ float  smx[WPB], ssum[WPB];  // per-wave partial m, s
  __shared__ float4 sacc[WPB][64];        // per-wave partial acc (1 KB each)

  const int pos  = blockIdx.x;
  const int wv   = threadIdx.x >> 6;
  const int lane = threadIdx.x & 63;
  const int l4   = lane << 2;

  // ---- every wave: load indices/mask, ballot-compact into own LDS slice ----
  bool active = false;
  int  my     = 0;
  if (lane == 0) {
    my = node_ids[pos];
    active = true;                               // self never masked
  } else if (lane <= NN) {
    my     = neighs[pos * NN + lane - 1];
    active = (mask[pos * NN + lane - 1] == 0);   // masked -> weight +0 -> skip
  }
  const unsigned long long bal = __ballot(active);
  const int K = (int)__popcll(bal);              // wave-uniform (SGPR)
  if (active)
    sidx[wv][(int)__popcll(bal & ((1ull << lane) - 1ull))] = my;
  // Same-wave LDS write->read: DS ops execute in order within a wave.
  const int cidx = sidx[wv][lane];               // lane k = survivor k's id
  const int swv  = __builtin_amdgcn_readfirstlane(wv);

  const float4 aw1 = *(const float4*)(a_w + l4);        // src half of a_w
  const float4 aw2 = *(const float4*)(a_w + H + l4);    // candidate half
  const float  ab  = a_b[0];
  const float4* __restrict__ embv = (const float4*)emb; // row = H/4 float4

  // Self row (survivor 0): needed by every wave for zsrc (L1 broadcast).
  const int    iself = __builtin_amdgcn_readlane(cidx, 0);
  const float4 es    = embv[(size_t)iself * (H / 4) + lane];

  // This wave's candidate rows, all loaded upfront (independent, in flight).
  float4 buf[JMAX];
#pragma unroll
  for (int j = 0; j < JMAX; ++j) {
    const int c = swv + WPB * j;
    if (c < K) {                                          // scalar guard
      const int ic = __builtin_amdgcn_readlane(cidx, c);  // SGPR row index
      buf[j] = embv[(size_t)ic * (H / 4) + lane];
    }
  }

  // Batched butterfly: zsrc + all candidate dots reduced together
  // (independent values -> DS ops pipeline instead of serializing).
  float red[NR];
  red[0] = es.x * aw1.x + es.y * aw1.y + es.z * aw1.z + es.w * aw1.w;
#pragma unroll
  for (int j = 0; j < JMAX; ++j) {
    const int c = swv + WPB * j;
    red[j + 1] = 0.f;
    if (c < K) {
      const float4 cur = buf[j];
      red[j + 1] = cur.x * aw2.x + cur.y * aw2.y +
                   cur.z * aw2.z + cur.w * aw2.w;
    }
  }
#pragma unroll
  for (int off = 32; off > 0; off >>= 1) {
#pragma unroll
    for (int t = 0; t < NR; ++t)
      red[t] += __shfl_xor(red[t], off, 64);
  }
  const float zsrc = red[0];

  // Two-pass softmax over this wave's (known) logits.
  float aj[JMAX];
  float m = -1e30f;
#pragma unroll
  for (int j = 0; j < JMAX; ++j) {
    const int c = swv + WPB * j;
    if (c < K) {
      const float z = zsrc + red[j + 1] + ab;
      aj[j] = (z > 0.f) ? z : SLOPE * z;          // LeakyReLU(0.2)
      m = fmaxf(m, aj[j]);
    }
  }
  float  s = 0.f;
  float4 acc = {0.f, 0.f, 0.f, 0.f};
#pragma unroll
  for (int j = 0; j < JMAX; ++j) {
    const int c = swv + WPB * j;
    if (c < K) {
      const float pr = __expf(aj[j] - m);
      s += pr;
      const float4 cur = buf[j];
      acc.x += pr * cur.x;
      acc.y += pr * cur.y;
      acc.z += pr * cur.z;
      acc.w += pr * cur.w;
    }
  }

  // ---- block merge of the 4 partials (single barrier) ----
  sacc[wv][lane] = acc;
  if (lane == 0) { smx[wv] = m; ssum[wv] = s; }
  __syncthreads();

  if (wv == 0) {
    const float M = fmaxf(fmaxf(smx[0], smx[1]), fmaxf(smx[2], smx[3]));
    float  S = 0.f;
    float4 o = {0.f, 0.f, 0.f, 0.f};
#pragma unroll
    for (int w = 0; w < WPB; ++w) {
      const float f = __expf(smx[w] - M);  // empty wave: exp(-1e30-M) = +0
      S += ssum[w] * f;
      const float4 a = sacc[w][lane];
      o.x += f * a.x; o.y += f * a.y; o.z += f * a.z; o.w += f * a.w;
    }
    const float inv = 1.f / S;
    o.x *= inv; o.y *= inv; o.z *= inv; o.w *= inv;
    *(float4*)(out + (size_t)pos * H + l4) = o;
  }
}

extern "C" void kernel_launch(void* const* d_in, const int* in_sizes, int n_in,
                              void* d_out, int out_size, void* d_ws, size_t ws_size,
                              hipStream_t stream) {
  const int*   node_ids = (const int*)d_in[0];
  const int*   neighs   = (const int*)d_in[1];
  const int*   mask     = (const int*)d_in[2];
  const float* emb      = (const float*)d_in[3];
  const float* a_w      = (const float*)d_in[4];
  const float* a_b      = (const float*)d_in[5];
  float*       out      = (float*)d_out;

  const int npos = in_sizes[0];           // B*S = 4096
  gat_kernel<<<npos, 256, 0, stream>>>(node_ids, neighs, mask, emb, a_w, a_b,
                                       out);
}